// Round 3
// baseline (120.493 us; speedup 1.0000x reference)
//
#include <hip/hip_runtime.h>

#define N_SAMP 1024
#define XD     128
#define HID    256

// ---------------------------------------------------------------------------
// Workspace layout (float indices):
//   [0, 1024)            S       per-i sum of exp(T1[i,j]) over j
//   [1024]               T0sum   sum over i of T1[i,i]  (diagonal, sans b2)
//   [2048, 2048+256K)    xpbT    (x @ W1x + b1)^T   [HID][N]  (k-major)
//   [next 256K)          ypT     (y @ W1y)^T        [HID][N]  (k-major)
// S/T0sum are zeroed by gemm_xy (ws is poisoned 0xAA before every launch).
// ---------------------------------------------------------------------------

// Kernel 1: the two small GEMMs, writing TRANSPOSED outputs. Thread k owns
// hidden unit k for 4 consecutive rows -> in k-major layout those 4 results
// are contiguous: one float4 store per array. Also zeroes S/T0sum.
__global__ __launch_bounds__(256) void gemm_xy(
    const float* __restrict__ x, const float* __restrict__ y,
    const float* __restrict__ W1, const float* __restrict__ b1,
    float* __restrict__ xpbT, float* __restrict__ ypT,
    float* __restrict__ S, float* __restrict__ T0sum)
{
    const int k  = threadIdx.x;        // hidden unit 0..255
    const int r0 = blockIdx.x * 4;     // 4 rows per block

    // Zero accumulators (256 blocks x 4 = 1024 S entries; block 0: T0sum).
    if (threadIdx.x < 4) S[blockIdx.x * 4 + threadIdx.x] = 0.f;
    if (blockIdx.x == 0 && threadIdx.x == 4) T0sum[0] = 0.f;

    float ax0 = 0.f, ax1 = 0.f, ax2 = 0.f, ax3 = 0.f;
    float ay0 = 0.f, ay1 = 0.f, ay2 = 0.f, ay3 = 0.f;

    #pragma unroll 4
    for (int d = 0; d < XD; ++d) {
        const float wx = W1[d * HID + k];            // coalesced over k
        const float wy = W1[(XD + d) * HID + k];
        ax0 = fmaf(x[(r0 + 0) * XD + d], wx, ax0);   // uniform -> s_load
        ax1 = fmaf(x[(r0 + 1) * XD + d], wx, ax1);
        ax2 = fmaf(x[(r0 + 2) * XD + d], wx, ax2);
        ax3 = fmaf(x[(r0 + 3) * XD + d], wx, ax3);
        ay0 = fmaf(y[(r0 + 0) * XD + d], wy, ay0);
        ay1 = fmaf(y[(r0 + 1) * XD + d], wy, ay1);
        ay2 = fmaf(y[(r0 + 2) * XD + d], wy, ay2);
        ay3 = fmaf(y[(r0 + 3) * XD + d], wy, ay3);
    }

    const float bk = b1[k];
    float4 xs = make_float4(ax0 + bk, ax1 + bk, ax2 + bk, ax3 + bk);
    float4 ys = make_float4(ay0, ay1, ay2, ay3);
    *(float4*)&xpbT[k * N_SAMP + r0] = xs;   // 16B-aligned (r0 % 4 == 0)
    *(float4*)&ypT [k * N_SAMP + r0] = ys;
}

// Kernel 2: pairwise relu-dot + exp row-sums.
// VALU-ISSUE-BOUND (round-2 post-mortem): so maximize useful-VALU density.
// Thread tile = 4i x 4j -> 16 accs; per k: 48 useful VALU vs 1 global
// float4 (x) + 1 LDS float4 (y, offset-immediate addressing = 0 VALU).
// Block = 128 threads (16 tj x 8 ti) covering 64 j x 32 i; grid 16x32 =
// 512 blocks = 2 blocks/CU (64 KB LDS/CU), 1 wave/SIMD — fine, the loop
// is issue-bound and unroll-8 keeps 8 independent loads in flight.
__global__ __launch_bounds__(128) void pair_lse(
    const float* __restrict__ ypT, const float* __restrict__ xpbT,
    const float* __restrict__ W2,
    float* __restrict__ S, float* __restrict__ T0sum)
{
    __shared__ float yl[HID * 32];         // [k][i] tile, 32 KB

    const int tid = threadIdx.x;
    const int tj  = tid & 15;              // j sub-block 0..15
    const int ti  = tid >> 4;              // i sub-block 0..7
    const int jb  = blockIdx.x * 64;
    const int ib  = blockIdx.y * 32;
    const int j0  = jb + tj * 4;
    const int i0  = ib + ti * 4;

    // Stage y tile: 256 k-rows x 32 i = 2048 float4s, 16 per thread.
    // 8 consecutive lanes cover one k-row (128 B contiguous).
    #pragma unroll
    for (int s = 0; s < 16; ++s) {
        const int f  = s * 128 + tid;
        const int k  = f >> 3;
        const int iq = (f & 7) * 4;
        *(float4*)&yl[k * 32 + iq] =
            *(const float4*)&ypT[k * N_SAMP + ib + iq];
    }
    __syncthreads();

    float acc[4][4];
    #pragma unroll
    for (int a = 0; a < 4; ++a)
        #pragma unroll
        for (int b = 0; b < 4; ++b) acc[a][b] = 0.f;

    const int ti4 = ti * 4;

    #pragma unroll 8
    for (int k = 0; k < HID; ++k) {
        const float4 xv = *(const float4*)&xpbT[k * N_SAMP + j0]; // L2/L1
        const float4 yv = *(const float4*)&yl[k * 32 + ti4];      // ds b128
        const float  w  = W2[k];                                  // s_load
        const float xs[4] = {xv.x, xv.y, xv.z, xv.w};
        const float ys[4] = {yv.x, yv.y, yv.z, yv.w};
        #pragma unroll
        for (int a = 0; a < 4; ++a)
            #pragma unroll
            for (int b = 0; b < 4; ++b)
                acc[a][b] = fmaf(fmaxf(ys[a] + xs[b], 0.f), w, acc[a][b]);
    }

    // Row sums of exp over this thread's 4 j's, then across the 16 tj
    // lanes (contiguous within a wave), then one atomic per i per block.
    // |acc| ~ O(1): exp without max-shift is safe in f32.
    #pragma unroll
    for (int a = 0; a < 4; ++a) {
        float e = __expf(acc[a][0]) + __expf(acc[a][1])
                + __expf(acc[a][2]) + __expf(acc[a][3]);
        #pragma unroll
        for (int off = 8; off; off >>= 1) e += __shfl_xor(e, off, 16);
        if (tj == 0) atomicAdd(&S[i0 + a], e);
    }

    // Diagonal (T0): i-range [bi*32,+32) sits inside j-range [bj*64,+64)
    // iff bj == bi>>1. Compile-time acc indices only (no scratch spill).
    if ((int)blockIdx.x == (int)(blockIdx.y >> 1)) {
        float dv = 0.f;
        #pragma unroll
        for (int a = 0; a < 4; ++a) {
            const int dd = i0 + a - j0;
            float t = 0.f;
            if      (dd == 0) t = acc[a][0];
            else if (dd == 1) t = acc[a][1];
            else if (dd == 2) t = acc[a][2];
            else if (dd == 3) t = acc[a][3];
            dv += t;
        }
        #pragma unroll
        for (int off = 32; off; off >>= 1) dv += __shfl_xor(dv, off, 64);
        if ((tid & 63) == 0) atomicAdd(T0sum, dv);
    }
}

// Kernel 3: lse[i] = log(S[i]); combine means. Single block.
__global__ __launch_bounds__(256) void finalize(
    const float* __restrict__ S, const float* __restrict__ T0sum,
    const float* __restrict__ b2, float* __restrict__ out)
{
    __shared__ float red[4];
    const int tid = threadIdx.x;

    float ls = 0.f;
    for (int i = tid; i < N_SAMP; i += 256) ls += logf(S[i]);
    #pragma unroll
    for (int off = 32; off; off >>= 1) ls += __shfl_xor(ls, off, 64);
    if ((tid & 63) == 0) red[tid >> 6] = ls;
    __syncthreads();

    if (tid == 0) {
        const float lse_sum = red[0] + red[1] + red[2] + red[3];
        const float t0_mean  = T0sum[0] / (float)N_SAMP + b2[0];
        const float lse_mean = lse_sum / (float)N_SAMP + b2[0] - logf((float)N_SAMP);
        out[0] = t0_mean - lse_mean;
    }
}

extern "C" void kernel_launch(void* const* d_in, const int* in_sizes, int n_in,
                              void* d_out, int out_size, void* d_ws, size_t ws_size,
                              hipStream_t stream)
{
    const float* x  = (const float*)d_in[0];
    const float* y  = (const float*)d_in[1];
    const float* W1 = (const float*)d_in[2];
    const float* b1 = (const float*)d_in[3];
    const float* W2 = (const float*)d_in[4];
    const float* b2 = (const float*)d_in[5];

    float* ws   = (float*)d_ws;
    float* S    = ws;                          // 1024 floats
    float* T0s  = ws + 1024;                   // 1 float
    float* xpbT = ws + 2048;                   // [HID][N]
    float* ypT  = ws + 2048 + HID * N_SAMP;    // [HID][N]

    gemm_xy <<<dim3(N_SAMP / 4), dim3(256), 0, stream>>>(x, y, W1, b1,
                                                         xpbT, ypT, S, T0s);
    pair_lse<<<dim3(16, 32),     dim3(128), 0, stream>>>(ypT, xpbT, W2, S, T0s);
    finalize<<<dim3(1),          dim3(256), 0, stream>>>(S, T0s, b2, (float*)d_out);
}